// Round 1
// baseline (10136.038 us; speedup 1.0000x reference)
//
#include <hip/hip_runtime.h>
#include <math.h>

// Problem constants
#define Bb 16
#define Nn 64
#define Dd 4
#define Tt 40
#define Ll 10
#define Hh 128
#define Kk 4
#define Ee (Nn*(Nn-1))   // 4032

__device__ __forceinline__ float tanh_fast(float x){
    float ax = fabsf(x);
    float e  = __expf(-2.0f*ax);
    float r  = (1.0f - e) / (1.0f + e);
    return x >= 0.0f ? r : -r;
}
__device__ __forceinline__ float sigmoid_fast(float x){
    return 1.0f / (1.0f + __expf(-x));
}

// ---------------------------------------------------------------------------
// Kernel A: SR[bn][k][sr][h] = sum_f hidden[bn][f] * msg_W1[k][sr*128+f][h]
// sr=0: send-half of W1, sr=1: recv-half. One 128-thread half-block per row.
// ---------------------------------------------------------------------------
__global__ void __launch_bounds__(256) kA(const float* __restrict__ hidden,
                                          const float* __restrict__ W1,
                                          float* __restrict__ SR){
    int p  = blockIdx.x*2 + (threadIdx.x >> 7);  // row id, 0..8191
    int h  = threadIdx.x & 127;
    int sr = p & 1;
    int k  = (p >> 1) & 3;
    int bn = p >> 3;
    const float* hid = hidden + bn*Hh;
    const float* w   = W1 + (k*256 + sr*128)*Hh + h;
    float acc = 0.0f;
#pragma unroll 8
    for (int f = 0; f < Hh; ++f)
        acc += hid[f] * w[f*Hh];
    SR[p*Hh + h] = acc;
}

// ---------------------------------------------------------------------------
// Kernel B: per (b, recv n): for the 63 incoming edges, compute
//   m1 = tanh(S[send] + R[n] + b1); m2 = tanh(m1 @ W2[k] + b2)
//   agg[b,n,:] = sum_e sum_k rel[b,e,k] * m2 / (K*D)
// Register-tiled GEMM: m1T[f][e] (LDS, 32KB) x W2 slab (LDS, 16KB),
// thread tile = 8 edges x 4 h. Edge 63 is a zero dummy (rel weight 0).
// ---------------------------------------------------------------------------
#define FMA4(d, s, v) { (d).x += (s)*(v).x; (d).y += (s)*(v).y; (d).z += (s)*(v).z; (d).w += (s)*(v).w; }

__global__ void __launch_bounds__(256) kB(const float* __restrict__ SR,
                                          const float* __restrict__ W2,
                                          const float* __restrict__ b1,
                                          const float* __restrict__ b2,
                                          const float* __restrict__ rel,
                                          const int*   __restrict__ send_idx,
                                          float* __restrict__ agg){
    __shared__ float m1T[128*64];   // [f][e], e padded to 64
    __shared__ float w2h[32*128];   // W2 slab [f_local][h]; reused as aggpart at end

    const int b   = blockIdx.x >> 6;
    const int n   = blockIdx.x & 63;
    const int tid = threadIdx.x;
    const int eg  = tid >> 5;        // 0..7  (edge group of 8)
    const int hg  = tid & 31;        // 0..31 (h group of 4)

    // mapping for m1T construction: thread -> (edge me, f-range [mfb,mfb+32))
    const int  me   = tid >> 2;           // 0..63
    const int  mfb  = (tid & 3) * 32;
    const bool mval = (me < 63);
    int msend = 0;
    if (mval) msend = send_idx[n*63 + me];

    float4 aggacc = make_float4(0.f, 0.f, 0.f, 0.f);

    for (int k = 0; k < Kk; ++k){
        __syncthreads();  // previous k finished reading m1T
        // ---- build m1T[f][me] for this k ----
        if (mval){
            const float4* Sr  = (const float4*)(SR + ((b*64+msend)*8 + k*2    )*Hh) + (mfb>>2);
            const float4* Rr  = (const float4*)(SR + ((b*64+n    )*8 + k*2 + 1)*Hh) + (mfb>>2);
            const float4* b1r = (const float4*)(b1 + k*Hh) + (mfb>>2);
#pragma unroll
            for (int i = 0; i < 8; ++i){
                float4 sv = Sr[i], rv = Rr[i], bv = b1r[i];
                int f = mfb + i*4;
                m1T[(f+0)*64 + me] = tanh_fast(sv.x + rv.x + bv.x);
                m1T[(f+1)*64 + me] = tanh_fast(sv.y + rv.y + bv.y);
                m1T[(f+2)*64 + me] = tanh_fast(sv.z + rv.z + bv.z);
                m1T[(f+3)*64 + me] = tanh_fast(sv.w + rv.w + bv.w);
            }
        } else {
#pragma unroll
            for (int i = 0; i < 32; ++i) m1T[(mfb+i)*64 + 63] = 0.0f;
        }

        float4 dot[8];
#pragma unroll
        for (int es = 0; es < 8; ++es) dot[es] = make_float4(0.f,0.f,0.f,0.f);

        for (int q = 0; q < 4; ++q){
            __syncthreads();  // previous slab consumed (q=0: nothing pending)
            // stage W2[k][q*32 .. q*32+31][:] -> w2h (linear 16KB copy)
            const float4* src = (const float4*)(W2 + (k*Hh + q*32)*Hh);
            float4* dst = (float4*)w2h;
#pragma unroll
            for (int j = 0; j < 4; ++j) dst[tid + j*256] = src[tid + j*256];
            __syncthreads();  // slab ready (and m1T ready when q=0)

            const float4* m1v = (const float4*)m1T;
            const float4* w2v = (const float4*)w2h;
#pragma unroll 4
            for (int f = 0; f < 32; ++f){
                float4 bv = w2v[f*32 + hg];
                float4 a0 = m1v[(q*32+f)*16 + eg*2];
                float4 a1 = m1v[(q*32+f)*16 + eg*2 + 1];
                FMA4(dot[0], a0.x, bv); FMA4(dot[1], a0.y, bv);
                FMA4(dot[2], a0.z, bv); FMA4(dot[3], a0.w, bv);
                FMA4(dot[4], a1.x, bv); FMA4(dot[5], a1.y, bv);
                FMA4(dot[6], a1.z, bv); FMA4(dot[7], a1.w, bv);
            }
        }

        // ---- activation + rel-weighted accumulation ----
        float4 b2v = ((const float4*)(b2 + k*Hh))[hg];
#pragma unroll
        for (int es = 0; es < 8; ++es){
            int e = eg*8 + es;
            float rw = (e < 63) ? rel[(b*Ee + n*63 + e)*Kk + k] : 0.0f;
            aggacc.x += rw * tanh_fast(dot[es].x + b2v.x);
            aggacc.y += rw * tanh_fast(dot[es].y + b2v.y);
            aggacc.z += rw * tanh_fast(dot[es].z + b2v.z);
            aggacc.w += rw * tanh_fast(dot[es].w + b2v.w);
        }
    }

    // ---- reduce the 8 edge-groups (reuse w2h as aggpart[8][128]) ----
    __syncthreads();
    ((float4*)w2h)[eg*32 + hg] = aggacc;
    __syncthreads();
    if (tid < Hh){
        float s = 0.0f;
#pragma unroll
        for (int g = 0; g < 8; ++g) s += w2h[g*Hh + tid];
        agg[(b*64+n)*Hh + tid] = s * (1.0f/16.0f);   // /K then /D
    }
}

// ---------------------------------------------------------------------------
// Kernel C: per (b,n): GRU cell + 3-layer output MLP; input select
// (burn-in from data for t<T, closed-loop from prev pred for t>=T);
// writes new hidden, prev-pred, and (t>=T) the output slice.
// ---------------------------------------------------------------------------
__global__ void __launch_bounds__(128) kC(const float* __restrict__ data,
                                          const float* __restrict__ agg,
                                          float* __restrict__ hidden,
                                          float* __restrict__ prevpred,
                                          const float* __restrict__ Wr_in, const float* __restrict__ br_in,
                                          const float* __restrict__ Wi_in, const float* __restrict__ bi_in,
                                          const float* __restrict__ Wn_in, const float* __restrict__ bn_in,
                                          const float* __restrict__ Wr_h,  const float* __restrict__ Wi_h,
                                          const float* __restrict__ Wh_h,
                                          const float* __restrict__ Wo1,   const float* __restrict__ bo1,
                                          const float* __restrict__ Wo2,   const float* __restrict__ bo2,
                                          const float* __restrict__ Wo3,   const float* __restrict__ bo3,
                                          float* __restrict__ out, int t){
    __shared__ float aggL[Hh];
    __shared__ float buf[Hh];
    __shared__ float insL[Dd];

    const int bn = blockIdx.x;
    const int h  = threadIdx.x;

    aggL[h] = agg[bn*Hh + h];
    if (h < Dd){
        float v = (t < Tt) ? data[(bn*Dd + h)*Tt + t] : prevpred[bn*Dd + h];
        insL[h] = v;
    }
    __syncthreads();

    const float i0 = insL[0], i1 = insL[1], i2 = insL[2], i3 = insL[3];

    float rsum = br_in[h] + i0*Wr_in[0*Hh+h] + i1*Wr_in[1*Hh+h] + i2*Wr_in[2*Hh+h] + i3*Wr_in[3*Hh+h];
    float isum = bi_in[h] + i0*Wi_in[0*Hh+h] + i1*Wi_in[1*Hh+h] + i2*Wi_in[2*Hh+h] + i3*Wi_in[3*Hh+h];
    float nsum = bn_in[h] + i0*Wn_in[0*Hh+h] + i1*Wn_in[1*Hh+h] + i2*Wn_in[2*Hh+h] + i3*Wn_in[3*Hh+h];

    float rh = 0.f, ih = 0.f, hh = 0.f;
#pragma unroll 4
    for (int f = 0; f < Hh; ++f){
        float a = aggL[f];
        rh += a * Wr_h[f*Hh + h];
        ih += a * Wi_h[f*Hh + h];
        hh += a * Wh_h[f*Hh + h];
    }
    float r  = sigmoid_fast(rsum + rh);
    float ii = sigmoid_fast(isum + ih);
    float nn = tanh_fast(nsum + r*hh);
    float hold = hidden[bn*Hh + h];
    float hnew = (1.0f - ii)*nn + ii*hold;
    hidden[bn*Hh + h] = hnew;

    buf[h] = hnew;
    __syncthreads();
    float y1 = bo1[h];
#pragma unroll 4
    for (int f = 0; f < Hh; ++f) y1 += buf[f] * Wo1[f*Hh + h];
    y1 = fmaxf(y1, 0.0f);
    __syncthreads();
    buf[h] = y1;
    __syncthreads();
    float y2 = bo2[h];
#pragma unroll 4
    for (int f = 0; f < Hh; ++f) y2 += buf[f] * Wo2[f*Hh + h];
    y2 = fmaxf(y2, 0.0f);
    __syncthreads();
    buf[h] = y2;
    __syncthreads();
    if (h < Dd){
        float p = bo3[h];
#pragma unroll 4
        for (int f = 0; f < Hh; ++f) p += buf[f] * Wo3[f*Dd + h];
        p += insL[h];
        prevpred[bn*Dd + h] = p;
        if (t >= Tt) out[(bn*Dd + h)*Ll + (t - Tt)] = p;
    }
}

// ---------------------------------------------------------------------------
extern "C" void kernel_launch(void* const* d_in, const int* in_sizes, int n_in,
                              void* d_out, int out_size, void* d_ws, size_t ws_size,
                              hipStream_t stream){
    const float* data  = (const float*)d_in[0];
    const float* rel   = (const float*)d_in[1];
    const float* W1    = (const float*)d_in[2];
    const float* b1    = (const float*)d_in[3];
    const float* W2    = (const float*)d_in[4];
    const float* b2    = (const float*)d_in[5];
    const float* Wr_h  = (const float*)d_in[6];
    const float* Wi_h  = (const float*)d_in[7];
    const float* Wh_h  = (const float*)d_in[8];
    const float* Wr_in = (const float*)d_in[9];
    const float* br_in = (const float*)d_in[10];
    const float* Wi_in = (const float*)d_in[11];
    const float* bi_in = (const float*)d_in[12];
    const float* Wn_in = (const float*)d_in[13];
    const float* bn_in = (const float*)d_in[14];
    const float* Wo1   = (const float*)d_in[15];
    const float* bo1   = (const float*)d_in[16];
    const float* Wo2   = (const float*)d_in[17];
    const float* bo2   = (const float*)d_in[18];
    const float* Wo3   = (const float*)d_in[19];
    const float* bo3   = (const float*)d_in[20];
    const int* send_idx = (const int*)d_in[22];

    float* out = (float*)d_out;
    float* ws  = (float*)d_ws;

    // workspace layout (floats): hidden | prevpred | SR | agg
    float* hidden   = ws;                              // B*N*H      = 131072
    float* prevpred = hidden + Bb*Nn*Hh;               // B*N*D      = 4096
    float* SR       = prevpred + Bb*Nn*Dd;             // B*N*K*2*H  = 1048576
    float* agg      = SR + Bb*Nn*Kk*2*Hh;              // B*N*H      = 131072

    // hidden and prevpred carry state across steps -> zero them every launch
    hipMemsetAsync(hidden, 0, (Bb*Nn*Hh + Bb*Nn*Dd)*sizeof(float), stream);

    for (int t = 0; t < Tt + Ll; ++t){
        kA<<<4096, 256, 0, stream>>>(hidden, W1, SR);
        kB<<<1024, 256, 0, stream>>>(SR, W2, b1, b2, rel, send_idx, agg);
        kC<<<1024, 128, 0, stream>>>(data, agg, hidden, prevpred,
                                     Wr_in, br_in, Wi_in, bi_in, Wn_in, bn_in,
                                     Wr_h, Wi_h, Wh_h,
                                     Wo1, bo1, Wo2, bo2, Wo3, bo3, out, t);
    }
}

// Round 2
// 5527.329 us; speedup vs baseline: 1.8338x; 1.8338x over previous
//
#include <hip/hip_runtime.h>
#include <math.h>

// Problem constants
#define Bb 16
#define Nn 64
#define Dd 4
#define Tt 40
#define Ll 10
#define Hh 128
#define Kk 4
#define Ee (Nn*(Nn-1))   // 4032

typedef __attribute__((ext_vector_type(8))) short short8;
typedef __attribute__((ext_vector_type(4))) float f32x4;

__device__ __forceinline__ float tanh_fast(float x){
    float ax = fabsf(x);
    float e  = __expf(-2.0f*ax);
    float r  = (1.0f - e) / (1.0f + e);
    return x >= 0.0f ? r : -r;
}
__device__ __forceinline__ float sigmoid_fast(float x){
    return 1.0f / (1.0f + __expf(-x));
}
__device__ __forceinline__ unsigned short f2bf(float x){   // RNE f32->bf16
    unsigned int u = __float_as_uint(x);
    return (unsigned short)((u + 0x7FFFu + ((u >> 16) & 1u)) >> 16);
}

// ---------------------------------------------------------------------------
// Precompute: W2 (fp32 [K][128][128]) -> bf16 B-fragment layout for
// mfma_f32_16x16x32_bf16:  frag(k,kc,nt)[lane][i] = W2[k][kc*32+(lane>>4)*8+i]
//                                                     [nt*16+(lane&15)]
// Each fragment is 64 lanes x 16B contiguous.  8192 threads, 8 values each.
// ---------------------------------------------------------------------------
__global__ void __launch_bounds__(256) kW2f(const float* __restrict__ W2,
                                            unsigned short* __restrict__ W2f){
    int t    = blockIdx.x * 256 + threadIdx.x;   // 0..8191
    int lane = t & 63;
    int nt   = (t >> 6) & 7;
    int kc   = (t >> 9) & 3;
    int k    = (t >> 11) & 3;
    int col  = nt * 16 + (lane & 15);
    int fb   = kc * 32 + (lane >> 4) * 8;
    unsigned int w[4];
#pragma unroll
    for (int p = 0; p < 4; ++p){
        unsigned short lo = f2bf(W2[(k*Hh + fb + 2*p    )*Hh + col]);
        unsigned short hi = f2bf(W2[(k*Hh + fb + 2*p + 1)*Hh + col]);
        w[p] = (unsigned int)lo | ((unsigned int)hi << 16);
    }
    ((uint4*)W2f)[t] = make_uint4(w[0], w[1], w[2], w[3]);
}

// ---------------------------------------------------------------------------
// Kernel A: SR[bn][k][sr][h] = sum_f hidden[bn][f] * msg_W1[k][sr*128+f][h]
// ---------------------------------------------------------------------------
__global__ void __launch_bounds__(256) kA(const float* __restrict__ hidden,
                                          const float* __restrict__ W1,
                                          float* __restrict__ SR){
    int p  = blockIdx.x*2 + (threadIdx.x >> 7);  // row id, 0..8191
    int h  = threadIdx.x & 127;
    int sr = p & 1;
    int k  = (p >> 1) & 3;
    int bn = p >> 3;
    const float* hid = hidden + bn*Hh;
    const float* w   = W1 + (k*256 + sr*128)*Hh + h;
    float acc = 0.0f;
#pragma unroll 8
    for (int f = 0; f < Hh; ++f)
        acc += hid[f] * w[f*Hh];
    SR[p*Hh + h] = acc;
}

// ---------------------------------------------------------------------------
// Kernel B (MFMA): per (b, recv n):
//   m1[e][f] = tanh(S[send_e][k][f] + R[n][k][f] + b1[k][f])  (bf16, LDS,
//              XOR-swizzled granules; edge 63 = zero dummy)
//   m2f = m1 @ W2[k]  via mfma_f32_16x16x32_bf16 (fp32 accum)
//   agg[b,n,h] += rel[b,e,k] * tanh(m2f + b2[k][h]) / 16
// Wave w owns N-tiles {2w,2w+1} over all 4 edge-strips -> B-frags loaded once,
// agg reduce is two shfl_xor (no cross-wave reduction needed).
// ---------------------------------------------------------------------------
__global__ void __launch_bounds__(256) kB(const float* __restrict__ SR,
                                          const unsigned short* __restrict__ W2f,
                                          const float* __restrict__ b1,
                                          const float* __restrict__ b2,
                                          const float* __restrict__ rel,
                                          const int*   __restrict__ send_idx,
                                          float* __restrict__ agg){
    __shared__ unsigned short m1s[64*128];   // 16KB, swizzled bf16 [e][f]
    __shared__ float rel_s[256];             // [e][k], e=63 dummy -> 0
    __shared__ float b2s[Kk*Hh];             // 2KB

    const int b    = blockIdx.x >> 6;
    const int n    = blockIdx.x & 63;
    const int tid  = threadIdx.x;
    const int wave = tid >> 6;
    const int lane = tid & 63;
    const int nt0  = wave * 2;

    // stage rel (252 contiguous floats per (b,n)) and b2
    if (tid < 252) rel_s[tid] = rel[b*(Ee*Kk) + n*252 + tid];
    else           rel_s[tid] = 0.0f;
    if (tid < 128) ((float4*)b2s)[tid] = ((const float4*)b2)[tid];

    // build-phase mapping: thread -> edge (tid&63), granule group (tid>>6)
    const int be = tid & 63;
    const int bw = tid >> 6;
    int bsrow = 0;
    if (be < 63) bsrow = send_idx[n*63 + be];

    float aggacc[2] = {0.0f, 0.0f};

    for (int k = 0; k < Kk; ++k){
        __syncthreads();   // previous k's MFMA reads of m1s done
        // ---- build m1s (bf16, swizzled) ----
        if (be < 63){
            const float4* Sv = (const float4*)(SR + ((size_t)((b*64 + bsrow)*8 + k*2    ))*Hh);
            const float4* Rv = (const float4*)(SR + ((size_t)((b*64 + n    )*8 + k*2 + 1))*Hh);
            const float4* Cv = (const float4*)(b1 + k*Hh);
#pragma unroll
            for (int j = 0; j < 4; ++j){
                int g = bw*4 + j;              // granule: f in [g*8, g*8+8)
                float4 s0 = Sv[g*2], s1 = Sv[g*2+1];
                float4 r0 = Rv[g*2], r1 = Rv[g*2+1];
                float4 c0 = Cv[g*2], c1 = Cv[g*2+1];
                unsigned int w0 = (unsigned int)f2bf(tanh_fast(s0.x+r0.x+c0.x))
                                | ((unsigned int)f2bf(tanh_fast(s0.y+r0.y+c0.y)) << 16);
                unsigned int w1 = (unsigned int)f2bf(tanh_fast(s0.z+r0.z+c0.z))
                                | ((unsigned int)f2bf(tanh_fast(s0.w+r0.w+c0.w)) << 16);
                unsigned int w2 = (unsigned int)f2bf(tanh_fast(s1.x+r1.x+c1.x))
                                | ((unsigned int)f2bf(tanh_fast(s1.y+r1.y+c1.y)) << 16);
                unsigned int w3 = (unsigned int)f2bf(tanh_fast(s1.z+r1.z+c1.z))
                                | ((unsigned int)f2bf(tanh_fast(s1.w+r1.w+c1.w)) << 16);
                ((uint4*)m1s)[be*16 + (g ^ (be & 7))] = make_uint4(w0, w1, w2, w3);
            }
        } else {
#pragma unroll
            for (int j = 0; j < 4; ++j){
                int g = bw*4 + j;
                ((uint4*)m1s)[63*16 + (g ^ 7)] = make_uint4(0,0,0,0);
            }
        }
        __syncthreads();

        // ---- MFMA: 4 edge-strips x 2 N-tiles, K=128 in 4 chunks ----
        f32x4 acc[4][2];
#pragma unroll
        for (int s = 0; s < 4; ++s){ acc[s][0] = (f32x4)0.0f; acc[s][1] = (f32x4)0.0f; }

        const short8* W2v = (const short8*)W2f;
        const short8* m1v = (const short8*)m1s;
#pragma unroll
        for (int kc = 0; kc < 4; ++kc){
            short8 bf0 = W2v[((k*4 + kc)*8 + nt0    )*64 + lane];
            short8 bf1 = W2v[((k*4 + kc)*8 + nt0 + 1)*64 + lane];
#pragma unroll
            for (int s = 0; s < 4; ++s){
                int row  = s*16 + (lane & 15);
                int qidx = row*16 + ((kc*4 + (lane >> 4)) ^ (row & 7));
                short8 a = m1v[qidx];
                acc[s][0] = __builtin_amdgcn_mfma_f32_16x16x32_bf16(a, bf0, acc[s][0], 0, 0, 0);
                acc[s][1] = __builtin_amdgcn_mfma_f32_16x16x32_bf16(a, bf1, acc[s][1], 0, 0, 0);
            }
        }

        // ---- epilogue: tanh + rel-weighted accumulate ----
        float b2v0 = b2s[k*Hh + nt0*16       + (lane & 15)];
        float b2v1 = b2s[k*Hh + (nt0+1)*16   + (lane & 15)];
#pragma unroll
        for (int s = 0; s < 4; ++s){
#pragma unroll
            for (int r = 0; r < 4; ++r){
                int e = s*16 + ((lane >> 4) << 2) + r;   // C/D: row=(lane>>4)*4+reg
                float rw = rel_s[e*4 + k];
                aggacc[0] += rw * tanh_fast(acc[s][0][r] + b2v0);
                aggacc[1] += rw * tanh_fast(acc[s][1][r] + b2v1);
            }
        }
    }

    // reduce over the 4 lane-quadrants; lanes 0..15 hold h = nt*16 + lane
#pragma unroll
    for (int m = 0; m < 2; ++m){
        float v = aggacc[m];
        v += __shfl_xor(v, 16);
        v += __shfl_xor(v, 32);
        if (lane < 16)
            agg[(size_t)(b*64 + n)*Hh + (nt0 + m)*16 + lane] = v * (1.0f/16.0f);
    }
}

// ---------------------------------------------------------------------------
// Kernel C: per (b,n): GRU cell + 3-layer output MLP
// ---------------------------------------------------------------------------
__global__ void __launch_bounds__(128) kC(const float* __restrict__ data,
                                          const float* __restrict__ agg,
                                          float* __restrict__ hidden,
                                          float* __restrict__ prevpred,
                                          const float* __restrict__ Wr_in, const float* __restrict__ br_in,
                                          const float* __restrict__ Wi_in, const float* __restrict__ bi_in,
                                          const float* __restrict__ Wn_in, const float* __restrict__ bn_in,
                                          const float* __restrict__ Wr_h,  const float* __restrict__ Wi_h,
                                          const float* __restrict__ Wh_h,
                                          const float* __restrict__ Wo1,   const float* __restrict__ bo1,
                                          const float* __restrict__ Wo2,   const float* __restrict__ bo2,
                                          const float* __restrict__ Wo3,   const float* __restrict__ bo3,
                                          float* __restrict__ out, int t){
    __shared__ float aggL[Hh];
    __shared__ float buf[Hh];
    __shared__ float insL[Dd];

    const int bn = blockIdx.x;
    const int h  = threadIdx.x;

    aggL[h] = agg[bn*Hh + h];
    if (h < Dd){
        float v = (t < Tt) ? data[(bn*Dd + h)*Tt + t] : prevpred[bn*Dd + h];
        insL[h] = v;
    }
    __syncthreads();

    const float i0 = insL[0], i1 = insL[1], i2 = insL[2], i3 = insL[3];

    float rsum = br_in[h] + i0*Wr_in[0*Hh+h] + i1*Wr_in[1*Hh+h] + i2*Wr_in[2*Hh+h] + i3*Wr_in[3*Hh+h];
    float isum = bi_in[h] + i0*Wi_in[0*Hh+h] + i1*Wi_in[1*Hh+h] + i2*Wi_in[2*Hh+h] + i3*Wi_in[3*Hh+h];
    float nsum = bn_in[h] + i0*Wn_in[0*Hh+h] + i1*Wn_in[1*Hh+h] + i2*Wn_in[2*Hh+h] + i3*Wn_in[3*Hh+h];

    float rh = 0.f, ih = 0.f, hh = 0.f;
#pragma unroll 4
    for (int f = 0; f < Hh; ++f){
        float a = aggL[f];
        rh += a * Wr_h[f*Hh + h];
        ih += a * Wi_h[f*Hh + h];
        hh += a * Wh_h[f*Hh + h];
    }
    float r  = sigmoid_fast(rsum + rh);
    float ii = sigmoid_fast(isum + ih);
    float nn = tanh_fast(nsum + r*hh);
    float hold = hidden[bn*Hh + h];
    float hnew = (1.0f - ii)*nn + ii*hold;
    hidden[bn*Hh + h] = hnew;

    buf[h] = hnew;
    __syncthreads();
    float y1 = bo1[h];
#pragma unroll 4
    for (int f = 0; f < Hh; ++f) y1 += buf[f] * Wo1[f*Hh + h];
    y1 = fmaxf(y1, 0.0f);
    __syncthreads();
    buf[h] = y1;
    __syncthreads();
    float y2 = bo2[h];
#pragma unroll 4
    for (int f = 0; f < Hh; ++f) y2 += buf[f] * Wo2[f*Hh + h];
    y2 = fmaxf(y2, 0.0f);
    __syncthreads();
    buf[h] = y2;
    __syncthreads();
    if (h < Dd){
        float p = bo3[h];
#pragma unroll 4
        for (int f = 0; f < Hh; ++f) p += buf[f] * Wo3[f*Dd + h];
        p += insL[h];
        prevpred[bn*Dd + h] = p;
        if (t >= Tt) out[(bn*Dd + h)*Ll + (t - Tt)] = p;
    }
}

// ---------------------------------------------------------------------------
extern "C" void kernel_launch(void* const* d_in, const int* in_sizes, int n_in,
                              void* d_out, int out_size, void* d_ws, size_t ws_size,
                              hipStream_t stream){
    const float* data  = (const float*)d_in[0];
    const float* rel   = (const float*)d_in[1];
    const float* W1    = (const float*)d_in[2];
    const float* b1    = (const float*)d_in[3];
    const float* W2    = (const float*)d_in[4];
    const float* b2    = (const float*)d_in[5];
    const float* Wr_h  = (const float*)d_in[6];
    const float* Wi_h  = (const float*)d_in[7];
    const float* Wh_h  = (const float*)d_in[8];
    const float* Wr_in = (const float*)d_in[9];
    const float* br_in = (const float*)d_in[10];
    const float* Wi_in = (const float*)d_in[11];
    const float* bi_in = (const float*)d_in[12];
    const float* Wn_in = (const float*)d_in[13];
    const float* bn_in = (const float*)d_in[14];
    const float* Wo1   = (const float*)d_in[15];
    const float* bo1   = (const float*)d_in[16];
    const float* Wo2   = (const float*)d_in[17];
    const float* bo2   = (const float*)d_in[18];
    const float* Wo3   = (const float*)d_in[19];
    const float* bo3   = (const float*)d_in[20];
    const int* send_idx = (const int*)d_in[22];

    float* out = (float*)d_out;
    float* ws  = (float*)d_ws;

    // workspace layout (floats): hidden | prevpred | SR | agg | W2f(bf16)
    float* hidden   = ws;                              // B*N*H      = 131072
    float* prevpred = hidden + Bb*Nn*Hh;               // B*N*D      = 4096
    float* SR       = prevpred + Bb*Nn*Dd;             // B*N*K*2*H  = 1048576
    float* agg      = SR + Bb*Nn*Kk*2*Hh;              // B*N*H      = 131072
    unsigned short* W2f = (unsigned short*)(agg + Bb*Nn*Hh);  // 65536 ushort

    // hidden and prevpred carry state across steps -> zero them every launch
    hipMemsetAsync(hidden, 0, (Bb*Nn*Hh + Bb*Nn*Dd)*sizeof(float), stream);

    // W2 -> bf16 fragment layout (deterministic, every call)
    kW2f<<<32, 256, 0, stream>>>(W2, W2f);

    for (int t = 0; t < Tt + Ll; ++t){
        kA<<<4096, 256, 0, stream>>>(hidden, W1, SR);
        kB<<<1024, 256, 0, stream>>>(SR, W2f, b1, b2, rel, send_idx, agg);
        kC<<<1024, 128, 0, stream>>>(data, agg, hidden, prevpred,
                                     Wr_in, br_in, Wi_in, bi_in, Wn_in, bn_in,
                                     Wr_h, Wi_h, Wh_h,
                                     Wo1, bo1, Wo2, bo2, Wo3, bo3, out, t);
    }
}

// Round 3
// 5195.787 us; speedup vs baseline: 1.9508x; 1.0638x over previous
//
#include <hip/hip_runtime.h>
#include <math.h>

// Problem constants
#define Bb 16
#define Nn 64
#define Dd 4
#define Tt 40
#define Ll 10
#define Hh 128
#define Kk 4
#define Ee (Nn*(Nn-1))   // 4032
#define BNH (Bb*Nn*Hh)   // 131072

typedef __attribute__((ext_vector_type(8))) short short8;
typedef __attribute__((ext_vector_type(4))) float f32x4;

// division-free: tanh(x) = sign(x) * (1 - 2e/(1+e)), e = exp(-2|x|)
__device__ __forceinline__ float tanh_fast(float x){
    float e = __expf(-2.0f * fabsf(x));
    float r = __builtin_amdgcn_rcpf(1.0f + e);
    float t = fmaf(-2.0f * e, r, 1.0f);
    return copysignf(t, x);
}
__device__ __forceinline__ float sigmoid_fast(float x){
    return __builtin_amdgcn_rcpf(1.0f + __expf(-x));
}
__device__ __forceinline__ unsigned short f2bf(float x){   // RNE f32->bf16
    unsigned int u = __float_as_uint(x);
    return (unsigned short)((u + 0x7FFFu + ((u >> 16) & 1u)) >> 16);
}

// ---------------------------------------------------------------------------
// Precompute: W2 (fp32 [K][128][128]) -> bf16 B-fragment layout for
// mfma_f32_16x16x32_bf16:  frag(k,kc,nt)[lane][i] = W2[k][kc*32+(lane>>4)*8+i]
//                                                     [nt*16+(lane&15)]
// ---------------------------------------------------------------------------
__global__ void __launch_bounds__(256) kW2f(const float* __restrict__ W2,
                                            unsigned short* __restrict__ W2f){
    int t    = blockIdx.x * 256 + threadIdx.x;   // 0..8191
    int lane = t & 63;
    int nt   = (t >> 6) & 7;
    int kc   = (t >> 9) & 3;
    int k    = (t >> 11) & 3;
    int col  = nt * 16 + (lane & 15);
    int fb   = kc * 32 + (lane >> 4) * 8;
    unsigned int w[4];
#pragma unroll
    for (int p = 0; p < 4; ++p){
        unsigned short lo = f2bf(W2[(k*Hh + fb + 2*p    )*Hh + col]);
        unsigned short hi = f2bf(W2[(k*Hh + fb + 2*p + 1)*Hh + col]);
        w[p] = (unsigned int)lo | ((unsigned int)hi << 16);
    }
    ((uint4*)W2f)[t] = make_uint4(w[0], w[1], w[2], w[3]);
}

// ---------------------------------------------------------------------------
// Kernel A: SR[bn][k][sr][h] = sum_f hidden[bn][f] * msg_W1[k][sr*128+f][h]
// ---------------------------------------------------------------------------
__global__ void __launch_bounds__(256) kA(const float* __restrict__ hidden,
                                          const float* __restrict__ W1,
                                          float* __restrict__ SR){
    int p  = blockIdx.x*2 + (threadIdx.x >> 7);  // row id, 0..8191
    int h  = threadIdx.x & 127;
    int sr = p & 1;
    int k  = (p >> 1) & 3;
    int bn = p >> 3;
    const float* hid = hidden + bn*Hh;
    const float* w   = W1 + (k*256 + sr*128)*Hh + h;
    float acc = 0.0f;
#pragma unroll 8
    for (int f = 0; f < Hh; ++f)
        acc += hid[f] * w[f*Hh];
    SR[p*Hh + h] = acc;
}

// ---------------------------------------------------------------------------
// Kernel B (MFMA, k-split): block = (b, n, k).  4096 blocks, 256 threads.
//   m1[e][f] = tanh(S[send_e] + R[n] + b1[k])  -> bf16 LDS, XOR-swizzled
//   m2 = m1 @ W2[k]  (mfma_f32_16x16x32_bf16, fp32 accum)
//   aggp[k][b,n,h] = sum_e rel[b,e,k] * tanh(m2 + b2[k][h])
// Wave w owns N-tiles {2w, 2w+1} over all 4 edge-strips; agg reduce = 2 shfl.
// ---------------------------------------------------------------------------
__global__ void __launch_bounds__(256) kB(const float* __restrict__ SR,
                                          const unsigned short* __restrict__ W2f,
                                          const float* __restrict__ b1,
                                          const float* __restrict__ b2,
                                          const float* __restrict__ rel,
                                          const int*   __restrict__ send_idx,
                                          float* __restrict__ aggp){
    __shared__ unsigned short m1s[64*128];   // 16KB swizzled bf16 [e][f]
    __shared__ float rel_s[64];
    __shared__ float b2s[Hh];

    const int blk  = blockIdx.x;
    const int k    = blk & 3;
    const int n    = (blk >> 2) & 63;
    const int b    = blk >> 8;
    const int tid  = threadIdx.x;
    const int wave = tid >> 6;
    const int lane = tid & 63;
    const int nt0  = wave * 2;

    // stage rel column k (e=63 dummy -> 0) and b2 slice k
    if (tid < 63)       rel_s[tid] = rel[(b*Ee + n*63 + tid)*Kk + k];
    else if (tid == 63) rel_s[63]  = 0.0f;
    if (tid >= 64 && tid < 96)
        ((float4*)b2s)[tid - 64] = ((const float4*)(b2 + k*Hh))[tid - 64];

    // ---- build m1s: 4 lanes per edge (coalesced row reads) ----
    const int e  = wave*16 + (lane >> 2);   // 0..63
    const int fq = lane & 3;                // f quarter: granules fq*4..fq*4+3
    if (e < 63){
        int srow = send_idx[n*63 + e];
        const float4* Sv = (const float4*)(SR + ((size_t)((b*64 + srow)*8 + k*2    ))*Hh);
        const float4* Rv = (const float4*)(SR + ((size_t)((b*64 + n   )*8 + k*2 + 1))*Hh);
        const float4* Cv = (const float4*)(b1 + k*Hh);
#pragma unroll
        for (int j = 0; j < 4; ++j){
            int g = fq*4 + j;
            float4 s0 = Sv[g*2], s1 = Sv[g*2+1];
            float4 r0 = Rv[g*2], r1 = Rv[g*2+1];
            float4 c0 = Cv[g*2], c1 = Cv[g*2+1];
            unsigned int w0 = (unsigned int)f2bf(tanh_fast(s0.x+r0.x+c0.x))
                            | ((unsigned int)f2bf(tanh_fast(s0.y+r0.y+c0.y)) << 16);
            unsigned int w1 = (unsigned int)f2bf(tanh_fast(s0.z+r0.z+c0.z))
                            | ((unsigned int)f2bf(tanh_fast(s0.w+r0.w+c0.w)) << 16);
            unsigned int w2 = (unsigned int)f2bf(tanh_fast(s1.x+r1.x+c1.x))
                            | ((unsigned int)f2bf(tanh_fast(s1.y+r1.y+c1.y)) << 16);
            unsigned int w3 = (unsigned int)f2bf(tanh_fast(s1.z+r1.z+c1.z))
                            | ((unsigned int)f2bf(tanh_fast(s1.w+r1.w+c1.w)) << 16);
            ((uint4*)m1s)[e*16 + (g ^ (e & 7))] = make_uint4(w0, w1, w2, w3);
        }
    } else {
#pragma unroll
        for (int j = 0; j < 4; ++j)
            ((uint4*)m1s)[63*16 + ((fq*4 + j) ^ 7)] = make_uint4(0,0,0,0);
    }
    __syncthreads();

    // ---- MFMA: 4 edge-strips x 2 N-tiles, K=128 in 4 chunks ----
    f32x4 acc[4][2];
#pragma unroll
    for (int s = 0; s < 4; ++s){ acc[s][0] = (f32x4)0.0f; acc[s][1] = (f32x4)0.0f; }

    const short8* W2v = (const short8*)W2f;
    const short8* m1v = (const short8*)m1s;
#pragma unroll
    for (int kc = 0; kc < 4; ++kc){
        short8 bf0 = W2v[((k*4 + kc)*8 + nt0    )*64 + lane];
        short8 bf1 = W2v[((k*4 + kc)*8 + nt0 + 1)*64 + lane];
#pragma unroll
        for (int s = 0; s < 4; ++s){
            int row  = s*16 + (lane & 15);
            int qidx = row*16 + ((kc*4 + (lane >> 4)) ^ (row & 7));
            short8 a = m1v[qidx];
            acc[s][0] = __builtin_amdgcn_mfma_f32_16x16x32_bf16(a, bf0, acc[s][0], 0, 0, 0);
            acc[s][1] = __builtin_amdgcn_mfma_f32_16x16x32_bf16(a, bf1, acc[s][1], 0, 0, 0);
        }
    }

    // ---- epilogue: tanh + rel-weighted accumulate ----
    float b2v0 = b2s[nt0*16       + (lane & 15)];
    float b2v1 = b2s[(nt0+1)*16   + (lane & 15)];
    float aggacc[2] = {0.0f, 0.0f};
#pragma unroll
    for (int s = 0; s < 4; ++s){
#pragma unroll
        for (int r = 0; r < 4; ++r){
            int e2 = s*16 + ((lane >> 4) << 2) + r;   // C/D: row=(lane>>4)*4+reg
            float rw = rel_s[e2];
            aggacc[0] += rw * tanh_fast(acc[s][0][r] + b2v0);
            aggacc[1] += rw * tanh_fast(acc[s][1][r] + b2v1);
        }
    }

    // reduce the 4 lane-quadrants; lanes 0..15 hold h = nt*16 + lane
#pragma unroll
    for (int m = 0; m < 2; ++m){
        float v = aggacc[m];
        v += __shfl_xor(v, 16);
        v += __shfl_xor(v, 32);
        if (lane < 16)
            aggp[(size_t)k*BNH + (size_t)(b*64 + n)*Hh + (nt0 + m)*16 + lane] = v;
    }
}

// ---------------------------------------------------------------------------
// Kernel C: per (b,n): sum agg partials, GRU cell + 3-layer output MLP
// ---------------------------------------------------------------------------
__global__ void __launch_bounds__(128) kC(const float* __restrict__ data,
                                          const float* __restrict__ aggp,
                                          float* __restrict__ hidden,
                                          float* __restrict__ prevpred,
                                          const float* __restrict__ Wr_in, const float* __restrict__ br_in,
                                          const float* __restrict__ Wi_in, const float* __restrict__ bi_in,
                                          const float* __restrict__ Wn_in, const float* __restrict__ bn_in,
                                          const float* __restrict__ Wr_h,  const float* __restrict__ Wi_h,
                                          const float* __restrict__ Wh_h,
                                          const float* __restrict__ Wo1,   const float* __restrict__ bo1,
                                          const float* __restrict__ Wo2,   const float* __restrict__ bo2,
                                          const float* __restrict__ Wo3,   const float* __restrict__ bo3,
                                          float* __restrict__ out, int t){
    __shared__ float aggL[Hh];
    __shared__ float buf[Hh];
    __shared__ float insL[Dd];

    const int bn = blockIdx.x;
    const int h  = threadIdx.x;

    aggL[h] = (aggp[bn*Hh + h] + aggp[BNH + bn*Hh + h] +
               aggp[2*BNH + bn*Hh + h] + aggp[3*BNH + bn*Hh + h]) * (1.0f/16.0f);
    if (h < Dd){
        float v = (t < Tt) ? data[(bn*Dd + h)*Tt + t] : prevpred[bn*Dd + h];
        insL[h] = v;
    }
    __syncthreads();

    const float i0 = insL[0], i1 = insL[1], i2 = insL[2], i3 = insL[3];

    float rsum = br_in[h] + i0*Wr_in[0*Hh+h] + i1*Wr_in[1*Hh+h] + i2*Wr_in[2*Hh+h] + i3*Wr_in[3*Hh+h];
    float isum = bi_in[h] + i0*Wi_in[0*Hh+h] + i1*Wi_in[1*Hh+h] + i2*Wi_in[2*Hh+h] + i3*Wi_in[3*Hh+h];
    float nsum = bn_in[h] + i0*Wn_in[0*Hh+h] + i1*Wn_in[1*Hh+h] + i2*Wn_in[2*Hh+h] + i3*Wn_in[3*Hh+h];

    float rh = 0.f, ih = 0.f, hh = 0.f;
#pragma unroll 4
    for (int f = 0; f < Hh; ++f){
        float a = aggL[f];
        rh += a * Wr_h[f*Hh + h];
        ih += a * Wi_h[f*Hh + h];
        hh += a * Wh_h[f*Hh + h];
    }
    float r  = sigmoid_fast(rsum + rh);
    float ii = sigmoid_fast(isum + ih);
    float nn = tanh_fast(nsum + r*hh);
    float hold = hidden[bn*Hh + h];
    float hnew = (1.0f - ii)*nn + ii*hold;
    hidden[bn*Hh + h] = hnew;

    buf[h] = hnew;
    __syncthreads();
    float y1 = bo1[h];
#pragma unroll 4
    for (int f = 0; f < Hh; ++f) y1 += buf[f] * Wo1[f*Hh + h];
    y1 = fmaxf(y1, 0.0f);
    __syncthreads();
    buf[h] = y1;
    __syncthreads();
    float y2 = bo2[h];
#pragma unroll 4
    for (int f = 0; f < Hh; ++f) y2 += buf[f] * Wo2[f*Hh + h];
    y2 = fmaxf(y2, 0.0f);
    __syncthreads();
    buf[h] = y2;
    __syncthreads();
    if (h < Dd){
        float p = bo3[h];
#pragma unroll 4
        for (int f = 0; f < Hh; ++f) p += buf[f] * Wo3[f*Dd + h];
        p += insL[h];
        prevpred[bn*Dd + h] = p;
        if (t >= Tt) out[(bn*Dd + h)*Ll + (t - Tt)] = p;
    }
}

// ---------------------------------------------------------------------------
extern "C" void kernel_launch(void* const* d_in, const int* in_sizes, int n_in,
                              void* d_out, int out_size, void* d_ws, size_t ws_size,
                              hipStream_t stream){
    const float* data  = (const float*)d_in[0];
    const float* rel   = (const float*)d_in[1];
    const float* W1    = (const float*)d_in[2];
    const float* b1    = (const float*)d_in[3];
    const float* W2    = (const float*)d_in[4];
    const float* b2    = (const float*)d_in[5];
    const float* Wr_h  = (const float*)d_in[6];
    const float* Wi_h  = (const float*)d_in[7];
    const float* Wh_h  = (const float*)d_in[8];
    const float* Wr_in = (const float*)d_in[9];
    const float* br_in = (const float*)d_in[10];
    const float* Wi_in = (const float*)d_in[11];
    const float* bi_in = (const float*)d_in[12];
    const float* Wn_in = (const float*)d_in[13];
    const float* bn_in = (const float*)d_in[14];
    const float* Wo1   = (const float*)d_in[15];
    const float* bo1   = (const float*)d_in[16];
    const float* Wo2   = (const float*)d_in[17];
    const float* bo2   = (const float*)d_in[18];
    const float* Wo3   = (const float*)d_in[19];
    const float* bo3   = (const float*)d_in[20];
    const int* send_idx = (const int*)d_in[22];

    float* out = (float*)d_out;
    float* ws  = (float*)d_ws;

    // workspace layout (floats): hidden | prevpred | SR | aggp[4] | W2f(bf16)
    float* hidden   = ws;                              // 131072
    float* prevpred = hidden + BNH;                    // 4096
    float* SR       = prevpred + Bb*Nn*Dd;             // 1048576
    float* aggp     = SR + Bb*Nn*Kk*2*Hh;              // 4*131072
    unsigned short* W2f = (unsigned short*)(aggp + 4*BNH);  // 65536 ushort

    // hidden and prevpred carry state across steps -> zero them every launch
    hipMemsetAsync(hidden, 0, (Bb*Nn*Hh + Bb*Nn*Dd)*sizeof(float), stream);

    // W2 -> bf16 fragment layout (deterministic, every call)
    kW2f<<<32, 256, 0, stream>>>(W2, W2f);

    for (int t = 0; t < Tt + Ll; ++t){
        kA<<<4096, 256, 0, stream>>>(hidden, W1, SR);
        kB<<<4096, 256, 0, stream>>>(SR, W2f, b1, b2, rel, send_idx, aggp);
        kC<<<1024, 128, 0, stream>>>(data, aggp, hidden, prevpred,
                                     Wr_in, br_in, Wi_in, bi_in, Wn_in, bn_in,
                                     Wr_h, Wi_h, Wh_h,
                                     Wo1, bo1, Wo2, bo2, Wo3, bo3, out, t);
    }
}

// Round 4
// 3101.949 us; speedup vs baseline: 3.2676x; 1.6750x over previous
//
#include <hip/hip_runtime.h>
#include <math.h>

// Problem constants
#define Bb 16
#define Nn 64
#define Dd 4
#define Tt 40
#define Ll 10
#define Hh 128
#define Kk 4
#define Ee (Nn*(Nn-1))   // 4032
#define BNH (Bb*Nn*Hh)   // 131072

typedef __attribute__((ext_vector_type(8))) short short8;
typedef __attribute__((ext_vector_type(4))) float f32x4;

// division-free: tanh(x) = sign(x) * (1 - 2e/(1+e)), e = exp(-2|x|)
__device__ __forceinline__ float tanh_fast(float x){
    float e = __expf(-2.0f * fabsf(x));
    float r = __builtin_amdgcn_rcpf(1.0f + e);
    float t = fmaf(-2.0f * e, r, 1.0f);
    return copysignf(t, x);
}
__device__ __forceinline__ float sigmoid_fast(float x){
    return __builtin_amdgcn_rcpf(1.0f + __expf(-x));
}
__device__ __forceinline__ unsigned short f2bf(float x){   // RNE f32->bf16
    unsigned int u = __float_as_uint(x);
    return (unsigned short)((u + 0x7FFFu + ((u >> 16) & 1u)) >> 16);
}

// ---------------------------------------------------------------------------
// Precompute: W2 (fp32 [K][128][128]) -> bf16 B-fragment layout for
// mfma_f32_16x16x32_bf16:  frag(k,kc,nt)[lane][i] = W2[k][kc*32+(lane>>4)*8+i]
//                                                     [nt*16+(lane&15)]
// ---------------------------------------------------------------------------
__global__ void __launch_bounds__(256) kW2f(const float* __restrict__ W2,
                                            unsigned short* __restrict__ W2f){
    int t    = blockIdx.x * 256 + threadIdx.x;   // 0..8191
    int lane = t & 63;
    int nt   = (t >> 6) & 7;
    int kc   = (t >> 9) & 3;
    int k    = (t >> 11) & 3;
    int col  = nt * 16 + (lane & 15);
    int fb   = kc * 32 + (lane >> 4) * 8;
    unsigned int w[4];
#pragma unroll
    for (int p = 0; p < 4; ++p){
        unsigned short lo = f2bf(W2[(k*Hh + fb + 2*p    )*Hh + col]);
        unsigned short hi = f2bf(W2[(k*Hh + fb + 2*p + 1)*Hh + col]);
        w[p] = (unsigned int)lo | ((unsigned int)hi << 16);
    }
    ((uint4*)W2f)[t] = make_uint4(w[0], w[1], w[2], w[3]);
}

// ---------------------------------------------------------------------------
// Kernel A (tiled): block = (ksr 0..7, bn-tile of 32).  256 blocks.
// SR[(bn*8 + ksr)*128 + h] = sum_f hidden[bn][f] * W1[ksr*128 + f][h]
// hidden tile transposed into LDS; thread = (h, row-half), 16 acc registers.
// ---------------------------------------------------------------------------
__global__ void __launch_bounds__(256) kA(const float* __restrict__ hidden,
                                          const float* __restrict__ W1,
                                          float* __restrict__ SR){
    __shared__ float hidT[128][36];   // [f][r], padded

    const int blk = blockIdx.x;
    const int ksr = blk & 7;
    const int bn0 = (blk >> 3) * 32;
    const int tid = threadIdx.x;

    {   // load hidden[bn0..bn0+32)[:] transposed
        int r  = tid >> 3;           // 0..31
        int f0 = (tid & 7) * 16;
        const float4* src = (const float4*)(hidden + (size_t)(bn0 + r)*Hh + f0);
        float4 v0 = src[0], v1 = src[1], v2 = src[2], v3 = src[3];
        hidT[f0+ 0][r]=v0.x; hidT[f0+ 1][r]=v0.y; hidT[f0+ 2][r]=v0.z; hidT[f0+ 3][r]=v0.w;
        hidT[f0+ 4][r]=v1.x; hidT[f0+ 5][r]=v1.y; hidT[f0+ 6][r]=v1.z; hidT[f0+ 7][r]=v1.w;
        hidT[f0+ 8][r]=v2.x; hidT[f0+ 9][r]=v2.y; hidT[f0+10][r]=v2.z; hidT[f0+11][r]=v2.w;
        hidT[f0+12][r]=v3.x; hidT[f0+13][r]=v3.y; hidT[f0+14][r]=v3.z; hidT[f0+15][r]=v3.w;
    }
    __syncthreads();

    const int h  = tid & 127;
    const int rp = (tid >> 7) * 16;   // row offset 0 or 16
    const float* w = W1 + (size_t)ksr*Hh*Hh + h;

    float acc[16];
#pragma unroll
    for (int i = 0; i < 16; ++i) acc[i] = 0.0f;

    for (int f = 0; f < Hh; ++f){
        float wv = w[(size_t)f*Hh];
        const float* hr = &hidT[f][rp];
#pragma unroll
        for (int i = 0; i < 16; ++i) acc[i] += hr[i]*wv;
    }
#pragma unroll
    for (int i = 0; i < 16; ++i)
        SR[((size_t)(bn0 + rp + i)*8 + ksr)*Hh + h] = acc[i];
}

// ---------------------------------------------------------------------------
// Kernel B (MFMA, register A-fragments): block = (b, n, k), 4096 blocks.
// Wave w owns edge-strip [16w,16w+16) x ALL 8 N-tiles:
//   - each lane builds its own A-fragments in registers (no m1 LDS!)
//   - W2f k-slice (32KB) staged once into LDS, shared by the 4 waves
//   - epilogue: tanh + rel weight, shfl reduce, 2KB cross-wave reduce
// ---------------------------------------------------------------------------
__global__ void __launch_bounds__(256) kB(const float* __restrict__ SR,
                                          const unsigned short* __restrict__ W2f,
                                          const float* __restrict__ b1,
                                          const float* __restrict__ b2,
                                          const float* __restrict__ rel,
                                          const int*   __restrict__ send_idx,
                                          float* __restrict__ aggp){
    __shared__ unsigned short w2s[32*512];   // 32KB: k-slice, 32 frags x 1KB
    __shared__ float rel_s[64];
    __shared__ float b2s[Hh];
    __shared__ float redu[4][Hh];            // 2KB cross-wave partials

    const int blk  = blockIdx.x;
    const int k    = blk & 3;
    const int n    = (blk >> 2) & 63;
    const int b    = blk >> 8;
    const int tid  = threadIdx.x;
    const int wave = tid >> 6;
    const int lane = tid & 63;

    // ---- stage W2f k-slice (linear 32KB), rel column, b2 row ----
    {
        const uint4* src = (const uint4*)(W2f + (size_t)k*16384);
        uint4* dst = (uint4*)w2s;
#pragma unroll
        for (int i = 0; i < 8; ++i) dst[tid + i*256] = src[tid + i*256];
    }
    if (tid < 63)       rel_s[tid] = rel[(b*Ee + n*63 + tid)*Kk + k];
    else if (tid == 63) rel_s[63]  = 0.0f;
    if (tid >= 64 && tid < 96)
        ((float4*)b2s)[tid - 64] = ((const float4*)(b2 + k*Hh))[tid - 64];

    // ---- build A-fragments in registers ----
    // lane holds edge e = wave*16 + (lane&15), f = kc*32 + (lane>>4)*8 + 0..7
    const int e  = wave*16 + (lane & 15);
    const int fo = (lane >> 4) * 8;
    short8 a[4];
    if (e < 63){
        int srow = send_idx[n*63 + e];
        const float* Sp = SR + ((size_t)((b*64 + srow)*8 + k*2    ))*Hh;
        const float* Rp = SR + ((size_t)((b*64 + n   )*8 + k*2 + 1))*Hh;
        const float* Cp = b1 + k*Hh;
#pragma unroll
        for (int kc = 0; kc < 4; ++kc){
            int f0 = kc*32 + fo;
            float4 s0 = *(const float4*)(Sp + f0), s1 = *(const float4*)(Sp + f0 + 4);
            float4 r0 = *(const float4*)(Rp + f0), r1 = *(const float4*)(Rp + f0 + 4);
            float4 c0 = *(const float4*)(Cp + f0), c1 = *(const float4*)(Cp + f0 + 4);
            union { short8 v; unsigned int u[4]; } av;
            av.u[0] = (unsigned int)f2bf(tanh_fast(s0.x+r0.x+c0.x))
                    | ((unsigned int)f2bf(tanh_fast(s0.y+r0.y+c0.y)) << 16);
            av.u[1] = (unsigned int)f2bf(tanh_fast(s0.z+r0.z+c0.z))
                    | ((unsigned int)f2bf(tanh_fast(s0.w+r0.w+c0.w)) << 16);
            av.u[2] = (unsigned int)f2bf(tanh_fast(s1.x+r1.x+c1.x))
                    | ((unsigned int)f2bf(tanh_fast(s1.y+r1.y+c1.y)) << 16);
            av.u[3] = (unsigned int)f2bf(tanh_fast(s1.z+r1.z+c1.z))
                    | ((unsigned int)f2bf(tanh_fast(s1.w+r1.w+c1.w)) << 16);
            a[kc] = av.v;
        }
    } else {
        union { short8 v; unsigned int u[4]; } z;
        z.u[0]=z.u[1]=z.u[2]=z.u[3]=0u;
#pragma unroll
        for (int kc = 0; kc < 4; ++kc) a[kc] = z.v;
    }
    __syncthreads();   // w2s/rel_s/b2s ready

    // ---- MFMA: this wave's strip x 8 N-tiles ----
    f32x4 acc[8];
#pragma unroll
    for (int nt = 0; nt < 8; ++nt) acc[nt] = (f32x4)0.0f;

    const short8* w2v = (const short8*)w2s;
#pragma unroll
    for (int kc = 0; kc < 4; ++kc){
#pragma unroll
        for (int nt = 0; nt < 8; ++nt){
            short8 bf = w2v[(kc*8 + nt)*64 + lane];
            acc[nt] = __builtin_amdgcn_mfma_f32_16x16x32_bf16(a[kc], bf, acc[nt], 0, 0, 0);
        }
    }

    // ---- epilogue: tanh + rel weight, reduce over strip rows ----
    // C/D: col = lane&15, row = (lane>>4)*4 + reg
    const int e2b = wave*16 + ((lane >> 4) << 2);
    float p[8];
#pragma unroll
    for (int nt = 0; nt < 8; ++nt){
        float b2v = b2s[nt*16 + (lane & 15)];
        float s = 0.0f;
#pragma unroll
        for (int r = 0; r < 4; ++r)
            s += rel_s[e2b + r] * tanh_fast(acc[nt][r] + b2v);
        s += __shfl_xor(s, 16);
        s += __shfl_xor(s, 32);
        p[nt] = s;
    }
    if (lane < 16){
#pragma unroll
        for (int nt = 0; nt < 8; ++nt) redu[wave][nt*16 + lane] = p[nt];
    }
    __syncthreads();
    if (tid < Hh){
        float v = redu[0][tid] + redu[1][tid] + redu[2][tid] + redu[3][tid];
        aggp[(size_t)k*BNH + (size_t)(b*64 + n)*Hh + tid] = v;
    }
}

// ---------------------------------------------------------------------------
// Kernel C (4 nodes/block): sum agg partials, GRU cell + 3-layer output MLP.
// 256 blocks x 128 threads; weight streams read once per 4 nodes.
// ---------------------------------------------------------------------------
__global__ void __launch_bounds__(128) kC(const float* __restrict__ data,
                                          const float* __restrict__ aggp,
                                          float* __restrict__ hidden,
                                          float* __restrict__ prevpred,
                                          const float* __restrict__ Wr_in, const float* __restrict__ br_in,
                                          const float* __restrict__ Wi_in, const float* __restrict__ bi_in,
                                          const float* __restrict__ Wn_in, const float* __restrict__ bn_in,
                                          const float* __restrict__ Wr_h,  const float* __restrict__ Wi_h,
                                          const float* __restrict__ Wh_h,
                                          const float* __restrict__ Wo1,   const float* __restrict__ bo1,
                                          const float* __restrict__ Wo2,   const float* __restrict__ bo2,
                                          const float* __restrict__ Wo3,   const float* __restrict__ bo3,
                                          float* __restrict__ out, int t){
    __shared__ float aggL[4][Hh];
    __shared__ float buf[4][Hh];
    __shared__ float insL[4][Dd];

    const int bn0 = blockIdx.x * 4;
    const int h   = threadIdx.x;

#pragma unroll
    for (int g = 0; g < 4; ++g){
        int bn = bn0 + g;
        aggL[g][h] = (aggp[bn*Hh + h] + aggp[BNH + bn*Hh + h] +
                      aggp[2*BNH + bn*Hh + h] + aggp[3*BNH + bn*Hh + h]) * (1.0f/16.0f);
    }
    if (h < 16){
        int g = h >> 2, d = h & 3;
        int bn = bn0 + g;
        insL[g][d] = (t < Tt) ? data[(bn*Dd + d)*Tt + t] : prevpred[bn*Dd + d];
    }
    __syncthreads();

    // gate hidden-side GEMVs, 4 nodes per weight load
    float rh[4] = {0,0,0,0}, ih[4] = {0,0,0,0}, hh[4] = {0,0,0,0};
    for (int f = 0; f < Hh; ++f){
        float wr = Wr_h[f*Hh + h], wi = Wi_h[f*Hh + h], wh = Wh_h[f*Hh + h];
#pragma unroll
        for (int g = 0; g < 4; ++g){
            float av = aggL[g][f];
            rh[g] += av*wr; ih[g] += av*wi; hh[g] += av*wh;
        }
    }

    const float wr0 = Wr_in[h],        wr1 = Wr_in[Hh + h],
                wr2 = Wr_in[2*Hh + h], wr3 = Wr_in[3*Hh + h];
    const float wi0 = Wi_in[h],        wi1 = Wi_in[Hh + h],
                wi2 = Wi_in[2*Hh + h], wi3 = Wi_in[3*Hh + h];
    const float wn0 = Wn_in[h],        wn1 = Wn_in[Hh + h],
                wn2 = Wn_in[2*Hh + h], wn3 = Wn_in[3*Hh + h];
    const float brv = br_in[h], biv = bi_in[h], bnv = bn_in[h];

#pragma unroll
    for (int g = 0; g < 4; ++g){
        float i0 = insL[g][0], i1 = insL[g][1], i2 = insL[g][2], i3 = insL[g][3];
        float r  = sigmoid_fast(brv + i0*wr0 + i1*wr1 + i2*wr2 + i3*wr3 + rh[g]);
        float ii = sigmoid_fast(biv + i0*wi0 + i1*wi1 + i2*wi2 + i3*wi3 + ih[g]);
        float nn = tanh_fast   (bnv + i0*wn0 + i1*wn1 + i2*wn2 + i3*wn3 + r*hh[g]);
        float hold = hidden[(bn0+g)*Hh + h];
        float hnew = (1.0f - ii)*nn + ii*hold;
        hidden[(bn0+g)*Hh + h] = hnew;
        buf[g][h] = hnew;
    }
    __syncthreads();

    float y1[4]; const float b1v = bo1[h];
#pragma unroll
    for (int g = 0; g < 4; ++g) y1[g] = b1v;
    for (int f = 0; f < Hh; ++f){
        float wv = Wo1[f*Hh + h];
#pragma unroll
        for (int g = 0; g < 4; ++g) y1[g] += buf[g][f]*wv;
    }
    __syncthreads();
#pragma unroll
    for (int g = 0; g < 4; ++g) buf[g][h] = fmaxf(y1[g], 0.0f);
    __syncthreads();

    float y2[4]; const float b2v = bo2[h];
#pragma unroll
    for (int g = 0; g < 4; ++g) y2[g] = b2v;
    for (int f = 0; f < Hh; ++f){
        float wv = Wo2[f*Hh + h];
#pragma unroll
        for (int g = 0; g < 4; ++g) y2[g] += buf[g][f]*wv;
    }
    __syncthreads();
#pragma unroll
    for (int g = 0; g < 4; ++g) buf[g][h] = fmaxf(y2[g], 0.0f);
    __syncthreads();

    if (h < 16){
        int g = h >> 2, d = h & 3;
        float pv = bo3[d];
        for (int f = 0; f < Hh; ++f) pv += buf[g][f]*Wo3[f*Dd + d];
        pv += insL[g][d];
        int bn = bn0 + g;
        prevpred[bn*Dd + d] = pv;
        if (t >= Tt) out[(bn*Dd + d)*Ll + (t - Tt)] = pv;
    }
}

// ---------------------------------------------------------------------------
extern "C" void kernel_launch(void* const* d_in, const int* in_sizes, int n_in,
                              void* d_out, int out_size, void* d_ws, size_t ws_size,
                              hipStream_t stream){
    const float* data  = (const float*)d_in[0];
    const float* rel   = (const float*)d_in[1];
    const float* W1    = (const float*)d_in[2];
    const float* b1    = (const float*)d_in[3];
    const float* W2    = (const float*)d_in[4];
    const float* b2    = (const float*)d_in[5];
    const float* Wr_h  = (const float*)d_in[6];
    const float* Wi_h  = (const float*)d_in[7];
    const float* Wh_h  = (const float*)d_in[8];
    const float* Wr_in = (const float*)d_in[9];
    const float* br_in = (const float*)d_in[10];
    const float* Wi_in = (const float*)d_in[11];
    const float* bi_in = (const float*)d_in[12];
    const float* Wn_in = (const float*)d_in[13];
    const float* bn_in = (const float*)d_in[14];
    const float* Wo1   = (const float*)d_in[15];
    const float* bo1   = (const float*)d_in[16];
    const float* Wo2   = (const float*)d_in[17];
    const float* bo2   = (const float*)d_in[18];
    const float* Wo3   = (const float*)d_in[19];
    const float* bo3   = (const float*)d_in[20];
    const int* send_idx = (const int*)d_in[22];

    float* out = (float*)d_out;
    float* ws  = (float*)d_ws;

    // workspace layout (floats): hidden | prevpred | SR | aggp[4] | W2f(bf16)
    float* hidden   = ws;                              // 131072
    float* prevpred = hidden + BNH;                    // 4096
    float* SR       = prevpred + Bb*Nn*Dd;             // 1048576
    float* aggp     = SR + Bb*Nn*Kk*2*Hh;              // 4*131072
    unsigned short* W2f = (unsigned short*)(aggp + 4*BNH);  // 65536 ushort

    // hidden and prevpred carry state across steps -> zero them every launch
    hipMemsetAsync(hidden, 0, (Bb*Nn*Hh + Bb*Nn*Dd)*sizeof(float), stream);

    // W2 -> bf16 fragment layout (deterministic, every call)
    kW2f<<<32, 256, 0, stream>>>(W2, W2f);

    for (int t = 0; t < Tt + Ll; ++t){
        kA<<<256, 256, 0, stream>>>(hidden, W1, SR);
        kB<<<4096, 256, 0, stream>>>(SR, W2f, b1, b2, rel, send_idx, aggp);
        kC<<<256, 128, 0, stream>>>(data, aggp, hidden, prevpred,
                                    Wr_in, br_in, Wi_in, bi_in, Wn_in, bn_in,
                                    Wr_h, Wi_h, Wh_h,
                                    Wo1, bo1, Wo2, bo2, Wo3, bo3, out, t);
    }
}

// Round 5
// 2719.251 us; speedup vs baseline: 3.7275x; 1.1407x over previous
//
#include <hip/hip_runtime.h>
#include <hip/hip_bf16.h>
#include <math.h>

// Problem constants
#define Bb 16
#define Nn 64
#define Dd 4
#define Tt 40
#define Ll 10
#define Hh 128
#define Kk 4
#define Ee (Nn*(Nn-1))   // 4032
#define BNH (Bb*Nn*Hh)   // 131072

typedef __attribute__((ext_vector_type(8))) short short8;
typedef __attribute__((ext_vector_type(4))) float f32x4;

#define AS1 __attribute__((address_space(1)))
#define AS3 __attribute__((address_space(3)))

// tanh(x) = 1 - 2/(exp(2x)+1)  — div/sign-free, exact at +-inf
__device__ __forceinline__ float tanh_fast(float x){
    float e = __expf(2.0f * x);
    float r = __builtin_amdgcn_rcpf(e + 1.0f);
    return fmaf(-2.0f, r, 1.0f);
}
__device__ __forceinline__ float sigmoid_fast(float x){
    return __builtin_amdgcn_rcpf(1.0f + __expf(-x));
}
__device__ __forceinline__ unsigned short f2bf(float x){   // RNE f32->bf16
    unsigned int u = __float_as_uint(x);
    return (unsigned short)((u + 0x7FFFu + ((u >> 16) & 1u)) >> 16);
}
// packed RNE f32x2 -> bf16x2 (v_cvt_pk_bf16_f32)
__device__ __forceinline__ unsigned int pack_bf2(float lo, float hi){
    union { __hip_bfloat162 h; unsigned int u; } cv;
    cv.h = __float22bfloat162_rn(make_float2(lo, hi));
    return cv.u;
}
// async global->LDS, 16B per lane
__device__ __forceinline__ void g2lds16(const void* g, void* l){
    __builtin_amdgcn_global_load_lds((const AS1 unsigned int*)g,
                                     (AS3 unsigned int*)l, 16, 0, 0);
}

// ---------------------------------------------------------------------------
// Precompute: W2 (fp32 [K][128][128]) -> bf16 B-fragment layout for
// mfma_f32_16x16x32_bf16:  frag(k,kc,nt)[lane][i] = W2[k][kc*32+(lane>>4)*8+i]
//                                                     [nt*16+(lane&15)]
// ---------------------------------------------------------------------------
__global__ void __launch_bounds__(256) kW2f(const float* __restrict__ W2,
                                            unsigned short* __restrict__ W2f){
    int t    = blockIdx.x * 256 + threadIdx.x;   // 0..8191
    int lane = t & 63;
    int nt   = (t >> 6) & 7;
    int kc   = (t >> 9) & 3;
    int k    = (t >> 11) & 3;
    int col  = nt * 16 + (lane & 15);
    int fb   = kc * 32 + (lane >> 4) * 8;
    unsigned int w[4];
#pragma unroll
    for (int p = 0; p < 4; ++p){
        unsigned short lo = f2bf(W2[(k*Hh + fb + 2*p    )*Hh + col]);
        unsigned short hi = f2bf(W2[(k*Hh + fb + 2*p + 1)*Hh + col]);
        w[p] = (unsigned int)lo | ((unsigned int)hi << 16);
    }
    ((uint4*)W2f)[t] = make_uint4(w[0], w[1], w[2], w[3]);
}

// ---------------------------------------------------------------------------
// Kernel A (tiled): block = (ksr 0..7, bn-tile of 32).  256 blocks.
//   v[row][h] = sum_f hidden[row][f] * W1[ksr*128+f][h]
// sr==0 (send): write fragment-major Sf[b][k][fg=h/8][node][h%8]
// sr==1 (recv): write row-major  Rr[b][k][node][h]  with b1 folded in
// ---------------------------------------------------------------------------
__global__ void __launch_bounds__(256) kA(const float* __restrict__ hidden,
                                          const float* __restrict__ W1,
                                          const float* __restrict__ b1,
                                          float* __restrict__ Sf,
                                          float* __restrict__ Rr){
    __shared__ float hidT[128][36];   // [f][r], padded

    const int blk = blockIdx.x;
    const int ksr = blk & 7;
    const int bn0 = (blk >> 3) * 32;
    const int tid = threadIdx.x;

    {   // load hidden[bn0..bn0+32)[:] transposed
        int r  = tid >> 3;           // 0..31
        int f0 = (tid & 7) * 16;
        const float4* src = (const float4*)(hidden + (size_t)(bn0 + r)*Hh + f0);
        float4 v0 = src[0], v1 = src[1], v2 = src[2], v3 = src[3];
        hidT[f0+ 0][r]=v0.x; hidT[f0+ 1][r]=v0.y; hidT[f0+ 2][r]=v0.z; hidT[f0+ 3][r]=v0.w;
        hidT[f0+ 4][r]=v1.x; hidT[f0+ 5][r]=v1.y; hidT[f0+ 6][r]=v1.z; hidT[f0+ 7][r]=v1.w;
        hidT[f0+ 8][r]=v2.x; hidT[f0+ 9][r]=v2.y; hidT[f0+10][r]=v2.z; hidT[f0+11][r]=v2.w;
        hidT[f0+12][r]=v3.x; hidT[f0+13][r]=v3.y; hidT[f0+14][r]=v3.z; hidT[f0+15][r]=v3.w;
    }
    __syncthreads();

    const int h  = tid & 127;
    const int rp = (tid >> 7) * 16;   // row offset 0 or 16
    const int k  = ksr >> 1;
    const int sr = ksr & 1;
    const float* w = W1 + (size_t)ksr*Hh*Hh + h;

    float acc[16];
#pragma unroll
    for (int i = 0; i < 16; ++i) acc[i] = 0.0f;

    for (int f = 0; f < Hh; ++f){
        float wv = w[(size_t)f*Hh];
        const float* hr = &hidT[f][rp];
#pragma unroll
        for (int i = 0; i < 16; ++i) acc[i] += hr[i]*wv;
    }

    const int b     = bn0 >> 6;
    const int node0 = (bn0 & 63) + rp;
    if (sr == 0){
        const int fg = h >> 3, fl = h & 7;
        float* base = Sf + ((size_t)((b*4 + k)*16 + fg)*64 + node0)*8 + fl;
#pragma unroll
        for (int i = 0; i < 16; ++i) base[i*8] = acc[i];
    } else {
        float bb = b1[k*Hh + h];
        float* base = Rr + ((size_t)(b*4 + k)*64 + node0)*128 + h;
#pragma unroll
        for (int i = 0; i < 16; ++i) base[i*128] = acc[i] + bb;
    }
}

// ---------------------------------------------------------------------------
// Kernel B (MFMA, register A-fragments): block = (b, n, k), 4096 blocks.
// Wave w owns edge-strip [16w,16w+16) x ALL 8 N-tiles:
//   - lane builds its own A-fragments from coalesced Sf + broadcast Rr
//   - W2f k-slice (32KB) staged via async global_load_lds
//   - epilogue: tanh + rel weight, shfl reduce, 2KB cross-wave reduce
// ---------------------------------------------------------------------------
__global__ void __launch_bounds__(256) kB(const float* __restrict__ Sf,
                                          const float* __restrict__ Rr,
                                          const unsigned short* __restrict__ W2f,
                                          const float* __restrict__ b2,
                                          const float* __restrict__ rel,
                                          const int*   __restrict__ send_idx,
                                          float* __restrict__ aggp){
    __shared__ unsigned short w2s[32*512];   // 32KB: k-slice, 32 frags x 1KB
    __shared__ float rel_s[64];
    __shared__ float b2s[Hh];
    __shared__ float redu[4][Hh];            // 2KB cross-wave partials

    const int blk  = blockIdx.x;
    const int k    = blk & 3;
    const int n    = (blk >> 2) & 63;
    const int b    = blk >> 8;
    const int tid  = threadIdx.x;
    const int wave = tid >> 6;
    const int lane = tid & 63;

    // ---- async stage W2f k-slice: 8 x 16B per thread, wave-linear dest ----
    {
        const uint4* src = (const uint4*)(W2f + (size_t)k*16384);
        uint4* dst = (uint4*)w2s;
#pragma unroll
        for (int i = 0; i < 8; ++i)
            g2lds16(src + tid + i*256, dst + tid + i*256);
    }
    if (tid < 63)       rel_s[tid] = rel[(b*Ee + n*63 + tid)*Kk + k];
    else if (tid == 63) rel_s[63]  = 0.0f;
    if (tid >= 64 && tid < 96)
        ((float4*)b2s)[tid - 64] = ((const float4*)(b2 + k*Hh))[tid - 64];

    // ---- build A-fragments in registers ----
    // lane: edge e = wave*16 + (lane&15), f-group fo = lane>>4 (8 features)
    const int e  = wave*16 + (lane & 15);
    const int fo = lane >> 4;
    short8 a[4];
    if (e < 63){
        int srow = send_idx[n*63 + e];
        const float* Sp = Sf + (size_t)((b*4 + k)*16)*512;       // + fg*512 + node*8
        const float* Rp = Rr + (size_t)((b*4 + k)*64 + n)*128;   // + f
#pragma unroll
        for (int kc = 0; kc < 4; ++kc){
            int fg = kc*4 + fo;
            const float4* sv = (const float4*)(Sp + fg*512 + srow*8);
            const float4* rv = (const float4*)(Rp + fg*8);
            float4 s0 = sv[0], s1 = sv[1];
            float4 r0 = rv[0], r1 = rv[1];
            union { short8 v; unsigned int u[4]; } av;
            av.u[0] = pack_bf2(tanh_fast(s0.x+r0.x), tanh_fast(s0.y+r0.y));
            av.u[1] = pack_bf2(tanh_fast(s0.z+r0.z), tanh_fast(s0.w+r0.w));
            av.u[2] = pack_bf2(tanh_fast(s1.x+r1.x), tanh_fast(s1.y+r1.y));
            av.u[3] = pack_bf2(tanh_fast(s1.z+r1.z), tanh_fast(s1.w+r1.w));
            a[kc] = av.v;
        }
    } else {
        union { short8 v; unsigned int u[4]; } z;
        z.u[0]=z.u[1]=z.u[2]=z.u[3]=0u;
#pragma unroll
        for (int kc = 0; kc < 4; ++kc) a[kc] = z.v;
    }
    __syncthreads();   // w2s (async loads) + rel_s/b2s ready

    // ---- MFMA: this wave's strip x 8 N-tiles ----
    f32x4 acc[8];
#pragma unroll
    for (int nt = 0; nt < 8; ++nt) acc[nt] = (f32x4)0.0f;

    const short8* w2v = (const short8*)w2s;
#pragma unroll
    for (int kc = 0; kc < 4; ++kc){
#pragma unroll
        for (int nt = 0; nt < 8; ++nt){
            short8 bf = w2v[(kc*8 + nt)*64 + lane];
            acc[nt] = __builtin_amdgcn_mfma_f32_16x16x32_bf16(a[kc], bf, acc[nt], 0, 0, 0);
        }
    }

    // ---- epilogue: tanh + rel weight, reduce over strip rows ----
    // C/D: col = lane&15, row = (lane>>4)*4 + reg
    const int e2b = wave*16 + ((lane >> 4) << 2);
    float p[8];
#pragma unroll
    for (int nt = 0; nt < 8; ++nt){
        float b2v = b2s[nt*16 + (lane & 15)];
        float s = 0.0f;
#pragma unroll
        for (int r = 0; r < 4; ++r)
            s += rel_s[e2b + r] * tanh_fast(acc[nt][r] + b2v);
        s += __shfl_xor(s, 16);
        s += __shfl_xor(s, 32);
        p[nt] = s;
    }
    if (lane < 16){
#pragma unroll
        for (int nt = 0; nt < 8; ++nt) redu[wave][nt*16 + lane] = p[nt];
    }
    __syncthreads();
    if (tid < Hh){
        float v = redu[0][tid] + redu[1][tid] + redu[2][tid] + redu[3][tid];
        aggp[(size_t)k*BNH + (size_t)(b*64 + n)*Hh + tid] = v;
    }
}

// ---------------------------------------------------------------------------
// Kernel C (4 nodes/block): sum agg partials, GRU cell + 3-layer output MLP.
// ---------------------------------------------------------------------------
__global__ void __launch_bounds__(128) kC(const float* __restrict__ data,
                                          const float* __restrict__ aggp,
                                          float* __restrict__ hidden,
                                          float* __restrict__ prevpred,
                                          const float* __restrict__ Wr_in, const float* __restrict__ br_in,
                                          const float* __restrict__ Wi_in, const float* __restrict__ bi_in,
                                          const float* __restrict__ Wn_in, const float* __restrict__ bn_in,
                                          const float* __restrict__ Wr_h,  const float* __restrict__ Wi_h,
                                          const float* __restrict__ Wh_h,
                                          const float* __restrict__ Wo1,   const float* __restrict__ bo1,
                                          const float* __restrict__ Wo2,   const float* __restrict__ bo2,
                                          const float* __restrict__ Wo3,   const float* __restrict__ bo3,
                                          float* __restrict__ out, int t){
    __shared__ float aggL[4][Hh];
    __shared__ float buf[4][Hh];
    __shared__ float insL[4][Dd];

    const int bn0 = blockIdx.x * 4;
    const int h   = threadIdx.x;

#pragma unroll
    for (int g = 0; g < 4; ++g){
        int bn = bn0 + g;
        aggL[g][h] = (aggp[bn*Hh + h] + aggp[BNH + bn*Hh + h] +
                      aggp[2*BNH + bn*Hh + h] + aggp[3*BNH + bn*Hh + h]) * (1.0f/16.0f);
    }
    if (h < 16){
        int g = h >> 2, d = h & 3;
        int bn = bn0 + g;
        insL[g][d] = (t < Tt) ? data[(bn*Dd + d)*Tt + t] : prevpred[bn*Dd + d];
    }
    __syncthreads();

    // gate hidden-side GEMVs, 4 nodes per weight load
    float rh[4] = {0,0,0,0}, ih[4] = {0,0,0,0}, hh[4] = {0,0,0,0};
    for (int f = 0; f < Hh; ++f){
        float wr = Wr_h[f*Hh + h], wi = Wi_h[f*Hh + h], wh = Wh_h[f*Hh + h];
#pragma unroll
        for (int g = 0; g < 4; ++g){
            float av = aggL[g][f];
            rh[g] += av*wr; ih[g] += av*wi; hh[g] += av*wh;
        }
    }

    const float wr0 = Wr_in[h],        wr1 = Wr_in[Hh + h],
                wr2 = Wr_in[2*Hh + h], wr3 = Wr_in[3*Hh + h];
    const float wi0 = Wi_in[h],        wi1 = Wi_in[Hh + h],
                wi2 = Wi_in[2*Hh + h], wi3 = Wi_in[3*Hh + h];
    const float wn0 = Wn_in[h],        wn1 = Wn_in[Hh + h],
                wn2 = Wn_in[2*Hh + h], wn3 = Wn_in[3*Hh + h];
    const float brv = br_in[h], biv = bi_in[h], bnv = bn_in[h];

#pragma unroll
    for (int g = 0; g < 4; ++g){
        float i0 = insL[g][0], i1 = insL[g][1], i2 = insL[g][2], i3 = insL[g][3];
        float r  = sigmoid_fast(brv + i0*wr0 + i1*wr1 + i2*wr2 + i3*wr3 + rh[g]);
        float ii = sigmoid_fast(biv + i0*wi0 + i1*wi1 + i2*wi2 + i3*wi3 + ih[g]);
        float nn = tanh_fast   (bnv + i0*wn0 + i1*wn1 + i2*wn2 + i3*wn3 + r*hh[g]);
        float hold = hidden[(bn0+g)*Hh + h];
        float hnew = (1.0f - ii)*nn + ii*hold;
        hidden[(bn0+g)*Hh + h] = hnew;
        buf[g][h] = hnew;
    }
    __syncthreads();

    float y1[4]; const float b1v = bo1[h];
#pragma unroll
    for (int g = 0; g < 4; ++g) y1[g] = b1v;
    for (int f = 0; f < Hh; ++f){
        float wv = Wo1[f*Hh + h];
#pragma unroll
        for (int g = 0; g < 4; ++g) y1[g] += buf[g][f]*wv;
    }
    __syncthreads();
#pragma unroll
    for (int g = 0; g < 4; ++g) buf[g][h] = fmaxf(y1[g], 0.0f);
    __syncthreads();

    float y2[4]; const float b2v = bo2[h];
#pragma unroll
    for (int g = 0; g < 4; ++g) y2[g] = b2v;
    for (int f = 0; f < Hh; ++f){
        float wv = Wo2[f*Hh + h];
#pragma unroll
        for (int g = 0; g < 4; ++g) y2[g] += buf[g][f]*wv;
    }
    __syncthreads();
#pragma unroll
    for (int g = 0; g < 4; ++g) buf[g][h] = fmaxf(y2[g], 0.0f);
    __syncthreads();

    if (h < 16){
        int g = h >> 2, d = h & 3;
        float pv = bo3[d];
        for (int f = 0; f < Hh; ++f) pv += buf[g][f]*Wo3[f*Dd + d];
        pv += insL[g][d];
        int bn = bn0 + g;
        prevpred[bn*Dd + d] = pv;
        if (t >= Tt) out[(bn*Dd + d)*Ll + (t - Tt)] = pv;
    }
}

// ---------------------------------------------------------------------------
extern "C" void kernel_launch(void* const* d_in, const int* in_sizes, int n_in,
                              void* d_out, int out_size, void* d_ws, size_t ws_size,
                              hipStream_t stream){
    const float* data  = (const float*)d_in[0];
    const float* rel   = (const float*)d_in[1];
    const float* W1    = (const float*)d_in[2];
    const float* b1    = (const float*)d_in[3];
    const float* W2    = (const float*)d_in[4];
    const float* b2    = (const float*)d_in[5];
    const float* Wr_h  = (const float*)d_in[6];
    const float* Wi_h  = (const float*)d_in[7];
    const float* Wh_h  = (const float*)d_in[8];
    const float* Wr_in = (const float*)d_in[9];
    const float* br_in = (const float*)d_in[10];
    const float* Wi_in = (const float*)d_in[11];
    const float* bi_in = (const float*)d_in[12];
    const float* Wn_in = (const float*)d_in[13];
    const float* bn_in = (const float*)d_in[14];
    const float* Wo1   = (const float*)d_in[15];
    const float* bo1   = (const float*)d_in[16];
    const float* Wo2   = (const float*)d_in[17];
    const float* bo2   = (const float*)d_in[18];
    const float* Wo3   = (const float*)d_in[19];
    const float* bo3   = (const float*)d_in[20];
    const int* send_idx = (const int*)d_in[22];

    float* out = (float*)d_out;
    float* ws  = (float*)d_ws;

    // workspace layout (floats): hidden | prevpred | Sf | Rr | aggp[4] | W2f
    float* hidden   = ws;                              // 131072
    float* prevpred = hidden + BNH;                    // 4096
    float* Sf       = prevpred + Bb*Nn*Dd;             // 524288
    float* Rr       = Sf + Bb*Kk*16*Nn*8;              // 524288
    float* aggp     = Rr + Bb*Kk*Nn*Hh;                // 4*131072
    unsigned short* W2f = (unsigned short*)(aggp + 4*BNH);  // 65536 ushort

    // hidden and prevpred carry state across steps -> zero them every launch
    hipMemsetAsync(hidden, 0, (Bb*Nn*Hh + Bb*Nn*Dd)*sizeof(float), stream);

    // W2 -> bf16 fragment layout (deterministic, every call)
    kW2f<<<32, 256, 0, stream>>>(W2, W2f);

    for (int t = 0; t < Tt + Ll; ++t){
        kA<<<256, 256, 0, stream>>>(hidden, W1, b1, Sf, Rr);
        kB<<<4096, 256, 0, stream>>>(Sf, Rr, W2f, b2, rel, send_idx, aggp);
        kC<<<256, 128, 0, stream>>>(data, aggp, hidden, prevpred,
                                    Wr_in, br_in, Wi_in, bi_in, Wn_in, bn_in,
                                    Wr_h, Wi_h, Wh_h,
                                    Wo1, bo1, Wo2, bo2, Wo3, bo3, out, t);
    }
}